// Round 1
// baseline (366.487 us; speedup 1.0000x reference)
//
#include <hip/hip_runtime.h>
#include <math.h>

#define B 32
#define S 512
#define E 512
#define FEAT 256
#define ATT 10
#define NCLS 8

// workspace layout (float offsets, all 16B-aligned)
#define OFF_EX      0ULL          // B*S*E           = 8388608
#define OFF_SCORES  8388608ULL    // B*S*ATT         = 163840
#define OFF_ATTN    8552448ULL    // B*S*ATT         = 163840
#define OFF_WHK     8716288ULL    // FEAT*E*3        = 393216
#define OFF_G       9109504ULL    // B*FEAT*ATT      = 81920
#define OFF_CPART   9191424ULL    // B*FEAT*4        = 32768
#define OFF_HC      9224192ULL    // B*FEAT          = 8192
// total ~36.9 MB of float scratch

// ---------------------------------------------------------------------------
// Wh [FEAT][E][3] -> Whk [FEAT][3*E] with kk = k*E + e (K-contiguous rows)
__global__ void k_transpose_wh(const float* __restrict__ Wh, float* __restrict__ Whk) {
    const int f = blockIdx.x;
    const float* src = Wh + (size_t)f * E * 3;
    float* dst = Whk + (size_t)f * E * 3;
    for (int kk = threadIdx.x; kk < E * 3; kk += blockDim.x) {
        const int k = kk >> 9;       // kk / 512
        const int e = kk & 511;      // kk % 512
        dst[kk] = src[e * 3 + k];
    }
}

// ---------------------------------------------------------------------------
// per (b,s): gather emb row -> ex, scores = ex . A, attn = softmax(scores)
__global__ void k_embed_scores(const int* __restrict__ x, const float* __restrict__ emb,
                               const float* __restrict__ A, float* __restrict__ ex,
                               float* __restrict__ scores, float* __restrict__ attn) {
    const int bs = blockIdx.x;              // 0 .. B*S-1
    const int tid = threadIdx.x;            // 256 threads
    const int row = x[bs];
    const float2 v = ((const float2*)(emb + (size_t)row * E))[tid];
    ((float2*)(ex + (size_t)bs * E))[tid] = v;

    const int e0 = tid * 2;
    const float* a0 = A + (size_t)e0 * ATT;
    float acc[ATT];
#pragma unroll
    for (int a = 0; a < ATT; ++a) acc[a] = v.x * a0[a] + v.y * a0[ATT + a];

#pragma unroll
    for (int a = 0; a < ATT; ++a)
        for (int off = 32; off > 0; off >>= 1) acc[a] += __shfl_down(acc[a], off);

    __shared__ float red[4][ATT];
    if ((tid & 63) == 0) {
#pragma unroll
        for (int a = 0; a < ATT; ++a) red[tid >> 6][a] = acc[a];
    }
    __syncthreads();
    if (tid == 0) {
        float sc[ATT], ev[ATT];
        float m = -1e30f;
#pragma unroll
        for (int a = 0; a < ATT; ++a) {
            sc[a] = red[0][a] + red[1][a] + red[2][a] + red[3][a];
            m = fmaxf(m, sc[a]);
        }
        float sum = 0.f;
#pragma unroll
        for (int a = 0; a < ATT; ++a) { ev[a] = expf(sc[a] - m); sum += ev[a]; }
        const float inv = 1.f / sum;
#pragma unroll
        for (int a = 0; a < ATT; ++a) {
            scores[(size_t)bs * ATT + a] = sc[a];
            attn[(size_t)bs * ATT + a] = ev[a] * inv;
        }
    }
}

// ---------------------------------------------------------------------------
// implicit-im2col conv GEMM, 128x128 tile, BK=16, 8x8 per thread, fp32.
// C[f,l] = sum_kk Whk[f,kk] * ex[b, l + kk/512, kk%512];  epilogue: per-f max
// over this tile's valid l -> Cpart[b,f,ntile]
__global__ __launch_bounds__(256) void k_conv(const float* __restrict__ Whk,
                                              const float* __restrict__ ex,
                                              float* __restrict__ Cpart) {
    const int b = blockIdx.x;
    const int fbase = blockIdx.y * 128;
    const int lbase = blockIdx.z * 128;
    __shared__ float As[16][132];
    __shared__ float Bs[16][132];
    const int tid = threadIdx.x;
    const int tx = tid & 15, ty = tid >> 4;
    const int mload = tid >> 1;
    const int seg = (tid & 1) * 8;
    const float* exb = ex + (size_t)b * S * E;

    float acc[8][8];
#pragma unroll
    for (int i = 0; i < 8; ++i)
#pragma unroll
        for (int j = 0; j < 8; ++j) acc[i][j] = 0.f;

    for (int kk0 = 0; kk0 < E * 3; kk0 += 16) {
        const int k = kk0 >> 9;
        const int e0 = kk0 & 511;
        {   // stage A tile: Whk rows are K-contiguous
            const float4* s = (const float4*)(Whk + (size_t)(fbase + mload) * (E * 3) + kk0 + seg);
            const float4 v0 = s[0], v1 = s[1];
            As[seg + 0][mload] = v0.x; As[seg + 1][mload] = v0.y;
            As[seg + 2][mload] = v0.z; As[seg + 3][mload] = v0.w;
            As[seg + 4][mload] = v1.x; As[seg + 5][mload] = v1.y;
            As[seg + 6][mload] = v1.z; As[seg + 7][mload] = v1.w;
        }
        {   // stage B tile: ex[b, l + k, e0..] with row bounds guard
            const int r = lbase + mload + k;
            float4 v0 = {0.f, 0.f, 0.f, 0.f}, v1 = {0.f, 0.f, 0.f, 0.f};
            if (r < S) {
                const float4* s = (const float4*)(exb + (size_t)r * E + e0 + seg);
                v0 = s[0]; v1 = s[1];
            }
            Bs[seg + 0][mload] = v0.x; Bs[seg + 1][mload] = v0.y;
            Bs[seg + 2][mload] = v0.z; Bs[seg + 3][mload] = v0.w;
            Bs[seg + 4][mload] = v1.x; Bs[seg + 5][mload] = v1.y;
            Bs[seg + 6][mload] = v1.z; Bs[seg + 7][mload] = v1.w;
        }
        __syncthreads();
#pragma unroll
        for (int j = 0; j < 16; ++j) {
            float ra[8], rb[8];
            *(float4*)&ra[0] = *(const float4*)&As[j][ty * 8];
            *(float4*)&ra[4] = *(const float4*)&As[j][ty * 8 + 4];
            *(float4*)&rb[0] = *(const float4*)&Bs[j][tx * 8];
            *(float4*)&rb[4] = *(const float4*)&Bs[j][tx * 8 + 4];
#pragma unroll
            for (int i = 0; i < 8; ++i)
#pragma unroll
                for (int jj = 0; jj < 8; ++jj) acc[i][jj] = fmaf(ra[i], rb[jj], acc[i][jj]);
        }
        __syncthreads();
    }

    // epilogue: per-f partial max over this tile's valid l (< S-2)
#pragma unroll
    for (int i = 0; i < 8; ++i) {
        float m = -1e30f;
#pragma unroll
        for (int jj = 0; jj < 8; ++jj) {
            const int l = lbase + tx * 8 + jj;
            if (l < S - 2) m = fmaxf(m, acc[i][jj]);
        }
#pragma unroll
        for (int off = 1; off < 16; off <<= 1) m = fmaxf(m, __shfl_xor(m, off, 16));
        if (tx == 0)
            Cpart[((size_t)(b * FEAT + fbase + ty * 8 + i) << 2) + blockIdx.z] = m;
    }
}

// ---------------------------------------------------------------------------
// G[b,f,a] = sum_t Wc[f,t] * scores[b,t,a]
__global__ void k_G(const float* __restrict__ scores, const float* __restrict__ Wc,
                    float* __restrict__ G) {
    const int f = blockIdx.x, b = blockIdx.y;
    const int tid = threadIdx.x;   // 64
    float acc[ATT];
#pragma unroll
    for (int a = 0; a < ATT; ++a) acc[a] = 0.f;
    for (int c = tid; c < S; c += 64) {
        const float w = Wc[(size_t)f * E + c];
        const float* sp = scores + ((size_t)b * S + c) * ATT;
#pragma unroll
        for (int a = 0; a < ATT; ++a) acc[a] = fmaf(w, sp[a], acc[a]);
    }
#pragma unroll
    for (int a = 0; a < ATT; ++a)
        for (int off = 32; off > 0; off >>= 1) acc[a] += __shfl_down(acc[a], off);
    if (tid == 0) {
#pragma unroll
        for (int a = 0; a < ATT; ++a) G[((size_t)b * FEAT + f) * ATT + a] = acc[a];
    }
}

// ---------------------------------------------------------------------------
// c[b,f] = max_l attn[b,l,:].G[b,f,:];  hc[b,f] = tanh(maxh + maxc + tb[f])
__global__ void k_hc(const float* __restrict__ attn, const float* __restrict__ G,
                     const float* __restrict__ Cpart, const float* __restrict__ tb,
                     float* __restrict__ hc) {
    const int f = blockIdx.x, b = blockIdx.y;
    const int tid = threadIdx.x;   // 64
    float g[ATT];
#pragma unroll
    for (int a = 0; a < ATT; ++a) g[a] = G[((size_t)b * FEAT + f) * ATT + a];
    float mc = -1e30f;
    for (int l = tid; l < S; l += 64) {
        const float* ap = attn + ((size_t)b * S + l) * ATT;
        float v = 0.f;
#pragma unroll
        for (int a = 0; a < ATT; ++a) v = fmaf(ap[a], g[a], v);
        mc = fmaxf(mc, v);
    }
#pragma unroll
    for (int off = 32; off > 0; off >>= 1) mc = fmaxf(mc, __shfl_xor(mc, off));
    if (tid == 0) {
        const float* cp = Cpart + (size_t)(b * FEAT + f) * 4;
        const float mh = fmaxf(fmaxf(cp[0], cp[1]), fmaxf(cp[2], cp[3]));
        hc[(size_t)b * FEAT + f] = tanhf(mh + mc + tb[f]);
    }
}

// ---------------------------------------------------------------------------
// out[b,n] = hc[b,:].Wfc[n,:] + bfc[n]
__global__ void k_out(const float* __restrict__ hc, const float* __restrict__ Wfc,
                      const float* __restrict__ bfc, float* __restrict__ out) {
    const int b = blockIdx.x;
    const int tid = threadIdx.x;   // 256
    __shared__ float hv[FEAT];
    __shared__ float ps[256];
    hv[tid] = hc[(size_t)b * FEAT + tid];
    __syncthreads();
    const int n = tid & 7;
    const int c = tid >> 3;
    float p = 0.f;
#pragma unroll
    for (int q = 0; q < 8; ++q) {
        const int f = c * 8 + q;
        p = fmaf(hv[f], Wfc[(size_t)n * FEAT + f], p);
    }
    ps[tid] = p;
    __syncthreads();
    if (tid < 8) {
        float s = bfc[tid];
        for (int q = 0; q < 32; ++q) s += ps[tid + 8 * q];
        out[(size_t)b * NCLS + tid] = s;
    }
}

// ---------------------------------------------------------------------------
extern "C" void kernel_launch(void* const* d_in, const int* in_sizes, int n_in,
                              void* d_out, int out_size, void* d_ws, size_t ws_size,
                              hipStream_t stream) {
    const int* x      = (const int*)d_in[0];
    const float* emb  = (const float*)d_in[1];
    const float* A    = (const float*)d_in[2];
    const float* Wh   = (const float*)d_in[3];
    const float* Wc   = (const float*)d_in[4];
    const float* tb   = (const float*)d_in[5];
    const float* Wfc  = (const float*)d_in[6];
    const float* bfc  = (const float*)d_in[7];
    float* out = (float*)d_out;
    float* ws  = (float*)d_ws;

    float* ex     = ws + OFF_EX;
    float* scores = ws + OFF_SCORES;
    float* attn   = ws + OFF_ATTN;
    float* Whk    = ws + OFF_WHK;
    float* G      = ws + OFF_G;
    float* Cpart  = ws + OFF_CPART;
    float* hc     = ws + OFF_HC;

    k_transpose_wh<<<FEAT, 256, 0, stream>>>(Wh, Whk);
    k_embed_scores<<<B * S, 256, 0, stream>>>(x, emb, A, ex, scores, attn);
    k_conv<<<dim3(B, 2, 4), 256, 0, stream>>>(Whk, ex, Cpart);
    k_G<<<dim3(FEAT, B), 64, 0, stream>>>(scores, Wc, G);
    k_hc<<<dim3(FEAT, B), 64, 0, stream>>>(attn, G, Cpart, tb, hc);
    k_out<<<B, 256, 0, stream>>>(hc, Wfc, bfc, out);
}

// Round 2
// 83.277 us; speedup vs baseline: 4.4008x; 4.4008x over previous
//
#include <hip/hip_runtime.h>
#include <math.h>

#define B 32
#define S 512
#define E 512
#define FEAT 256
#define ATT 10
#define NCLS 8

using short8 = __attribute__((ext_vector_type(8))) short;
using f32x4  = __attribute__((ext_vector_type(4))) float;

// RNE float->bf16 (finite inputs)
__device__ __forceinline__ unsigned short f2bf(float f) {
    unsigned int u = __float_as_uint(f);
    unsigned int r = (u + 0x7fffu + ((u >> 16) & 1u)) >> 16;
    return (unsigned short)r;
}

// async global->LDS, 16B per lane; lds dest must be wave-uniform (HW adds lane*16)
__device__ __forceinline__ void gl16(const void* g, void* l) {
    __builtin_amdgcn_global_load_lds(
        (const __attribute__((address_space(1))) unsigned int*)g,
        (__attribute__((address_space(3))) unsigned int*)l, 16, 0, 0);
}

// ---------------------------------------------------------------------------
// Wh [FEAT][E][3] fp32 -> Whk16 [FEAT][3*E] bf16 (kk = k*E + e), plus zero the
// 2-row ex16 tail pad (conv B-tiles read up to 2 rows past the last batch).
__global__ void k_prep(const float* __restrict__ Wh, unsigned short* __restrict__ Whk16,
                       unsigned short* __restrict__ ex16) {
    const int f = blockIdx.x;
    const float* src = Wh + (size_t)f * E * 3;
    unsigned short* dst = Whk16 + (size_t)f * E * 3;
    for (int kk = threadIdx.x; kk < E * 3; kk += 256) {
        const int k = kk >> 9;
        const int e = kk & 511;
        dst[kk] = f2bf(src[e * 3 + k]);
    }
    if (f == 0) {
        for (int i = threadIdx.x; i < 2 * E; i += 256)
            ex16[(size_t)B * S * E + i] = 0;
    }
}

// ---------------------------------------------------------------------------
// per (b,s), one wave: gather emb row, write bf16 ex, scores = ex.A (fp32),
// attn = softmax(scores)
__global__ void k_embed(const int* __restrict__ x, const float* __restrict__ emb,
                        const float* __restrict__ A, unsigned short* __restrict__ ex16,
                        float* __restrict__ scores, float* __restrict__ attn) {
    const int bs = blockIdx.x;
    const int lane = threadIdx.x;   // 64
    const int row = x[bs];
    const float4* src = (const float4*)(emb + (size_t)row * E);
    const float4 v0 = src[lane * 2], v1 = src[lane * 2 + 1];
    const float v[8] = {v0.x, v0.y, v0.z, v0.w, v1.x, v1.y, v1.z, v1.w};

    short8 sv;
#pragma unroll
    for (int j = 0; j < 8; ++j) sv[j] = (short)f2bf(v[j]);
    *(short8*)(ex16 + (size_t)bs * E + lane * 8) = sv;

    float acc[ATT];
#pragma unroll
    for (int a = 0; a < ATT; ++a) acc[a] = 0.f;
    const float* ap = A + (size_t)lane * 8 * ATT;
#pragma unroll
    for (int j = 0; j < 8; ++j)
#pragma unroll
        for (int a = 0; a < ATT; ++a) acc[a] = fmaf(v[j], ap[j * ATT + a], acc[a]);
#pragma unroll
    for (int a = 0; a < ATT; ++a)
#pragma unroll
        for (int off = 1; off < 64; off <<= 1) acc[a] += __shfl_xor(acc[a], off);

    if (lane == 0) {
        float m = -1e30f;
#pragma unroll
        for (int a = 0; a < ATT; ++a) m = fmaxf(m, acc[a]);
        float ev[ATT], sum = 0.f;
#pragma unroll
        for (int a = 0; a < ATT; ++a) { ev[a] = expf(acc[a] - m); sum += ev[a]; }
        const float inv = 1.f / sum;
#pragma unroll
        for (int a = 0; a < ATT; ++a) {
            scores[(size_t)bs * ATT + a] = acc[a];
            attn[(size_t)bs * ATT + a] = ev[a] * inv;
        }
    }
}

// ---------------------------------------------------------------------------
// bf16 MFMA implicit-im2col conv GEMM. C[f,l] = sum_kk Whk[f,kk]*ex[b,l+kk/E,kk%E]
// 128x128 tile, BK=64, 4 waves (2x2), wave tile 64x64 = 4x4 frags of 16x16x32.
// LDS: 2 bufs x (A 16KB + B 16KB) = 64KB, global_load_lds staging with XOR
// slot swizzle (slot ^= row&7) applied on global source + ds_read address.
// Epilogue: per-f max over valid l (<S-2) -> Cpart[b][f][z*2+wn] (8 partials).
__global__ __launch_bounds__(256) void k_conv(const unsigned short* __restrict__ Whk,
                                              const unsigned short* __restrict__ ex16,
                                              float* __restrict__ Cpart) {
    __shared__ unsigned short lds[2][16384];
    const int b = blockIdx.x;
    const int fbase = blockIdx.y * 128;
    const int lbase = blockIdx.z * 128;
    const int tid = threadIdx.x;
    const int wave = tid >> 6, lane = tid & 63;
    const int wm = wave >> 1, wn = wave & 1;
    const int lane15 = lane & 15, g4 = lane >> 4;
    const int rr = tid >> 3, slot = tid & 7;
    const unsigned short* exb = ex16 + (size_t)b * S * E;

    f32x4 acc[4][4];
#pragma unroll
    for (int mf = 0; mf < 4; ++mf)
#pragma unroll
        for (int nf = 0; nf < 4; ++nf) acc[mf][nf] = (f32x4){0.f, 0.f, 0.f, 0.f};

    auto stage = [&](int t, int d) {
        const int kk0 = t << 6;
        const int kpc = kk0 >> 9;      // which conv tap (0..2)
        const int e0  = kk0 & 511;
        unsigned short* la = &lds[d][0];
        unsigned short* lb = &lds[d][8192];
#pragma unroll
        for (int i = 0; i < 4; ++i) {   // A: Whk rows, 128B/row, 8 lanes/row
            const int r = i * 32 + rr;
            gl16(Whk + (size_t)(fbase + r) * (E * 3) + kk0 + ((slot ^ (r & 7)) << 3),
                 la + i * 2048 + wave * 512);
        }
#pragma unroll
        for (int i = 0; i < 4; ++i) {   // B: ex rows (l + tap), 64-elem chunk
            const int r = i * 32 + rr;
            gl16(exb + (size_t)(lbase + r + kpc) * E + e0 + ((slot ^ (r & 7)) << 3),
                 lb + i * 2048 + wave * 512);
        }
    };

    stage(0, 0);
    __syncthreads();   // compiler drains vmcnt(0) before s_barrier

    int cur = 0;
    for (int t = 0; t < 24; ++t) {
        if (t + 1 < 24) stage(t + 1, cur ^ 1);   // issue next-tile loads first
        const char* la = (const char*)&lds[cur][0];
        const char* lb = (const char*)&lds[cur][8192];
#pragma unroll
        for (int kh = 0; kh < 2; ++kh) {
            short8 av[4], bv[4];
#pragma unroll
            for (int mf = 0; mf < 4; ++mf) {
                const int row = wm * 64 + mf * 16 + lane15;
                av[mf] = *(const short8*)(la + row * 128 + ((((kh << 2) | g4) ^ (row & 7)) << 4));
            }
#pragma unroll
            for (int nf = 0; nf < 4; ++nf) {
                const int row = wn * 64 + nf * 16 + lane15;
                bv[nf] = *(const short8*)(lb + row * 128 + ((((kh << 2) | g4) ^ (row & 7)) << 4));
            }
#pragma unroll
            for (int mf = 0; mf < 4; ++mf)
#pragma unroll
                for (int nf = 0; nf < 4; ++nf)
                    acc[mf][nf] = __builtin_amdgcn_mfma_f32_16x16x32_bf16(
                        av[mf], bv[nf], acc[mf][nf], 0, 0, 0);
        }
        __syncthreads();
        cur ^= 1;
    }

    // epilogue: C/D layout col=lane&15, row=(lane>>4)*4+j (HW-verified m89/m91)
#pragma unroll
    for (int mf = 0; mf < 4; ++mf) {
#pragma unroll
        for (int j = 0; j < 4; ++j) {
            float m = -1e30f;
#pragma unroll
            for (int nf = 0; nf < 4; ++nf) {
                const int l = lbase + wn * 64 + nf * 16 + lane15;
                if (l < S - 2) m = fmaxf(m, acc[mf][nf][j]);
            }
#pragma unroll
            for (int off = 1; off < 16; off <<= 1) m = fmaxf(m, __shfl_xor(m, off));
            if (lane15 == 0) {
                const int f = fbase + wm * 64 + mf * 16 + g4 * 4 + j;
                Cpart[(((size_t)b * FEAT + f) << 3) + blockIdx.z * 2 + wn] = m;
            }
        }
    }
}

// ---------------------------------------------------------------------------
// fused c-branch + combine: g[a] = sum_t Wc[f,t]*scores[b,t,a];
// mc = max_l attn[b,l,:].g ; hc = tanh(max_h + mc + tb[f])
__global__ void k_chc(const float* __restrict__ scores, const float* __restrict__ attn,
                      const float* __restrict__ Wc, const float* __restrict__ Cpart,
                      const float* __restrict__ tb, float* __restrict__ hc) {
    const int f = blockIdx.x, b = blockIdx.y;
    const int lane = threadIdx.x;   // 64
    float g[ATT];
#pragma unroll
    for (int a = 0; a < ATT; ++a) g[a] = 0.f;
    for (int t = lane; t < S; t += 64) {
        const float w = Wc[(size_t)f * E + t];
        const float* sp = scores + ((size_t)b * S + t) * ATT;
#pragma unroll
        for (int a = 0; a < ATT; ++a) g[a] = fmaf(w, sp[a], g[a]);
    }
#pragma unroll
    for (int a = 0; a < ATT; ++a)
#pragma unroll
        for (int off = 1; off < 64; off <<= 1) g[a] += __shfl_xor(g[a], off);

    float mc = -1e30f;
    for (int l = lane; l < S; l += 64) {
        const float* ap = attn + ((size_t)b * S + l) * ATT;
        float v = 0.f;
#pragma unroll
        for (int a = 0; a < ATT; ++a) v = fmaf(ap[a], g[a], v);
        mc = fmaxf(mc, v);
    }
#pragma unroll
    for (int off = 1; off < 64; off <<= 1) mc = fmaxf(mc, __shfl_xor(mc, off));

    if (lane == 0) {
        const float* cp = Cpart + (((size_t)b * FEAT + f) << 3);
        float mh = cp[0];
#pragma unroll
        for (int q = 1; q < 8; ++q) mh = fmaxf(mh, cp[q]);
        hc[(size_t)b * FEAT + f] = tanhf(mh + mc + tb[f]);
    }
}

// ---------------------------------------------------------------------------
__global__ void k_out(const float* __restrict__ hc, const float* __restrict__ Wfc,
                      const float* __restrict__ bfc, float* __restrict__ out) {
    const int b = blockIdx.x;
    const int tid = threadIdx.x;   // 256
    __shared__ float hv[FEAT];
    __shared__ float ps[256];
    hv[tid] = hc[(size_t)b * FEAT + tid];
    __syncthreads();
    const int n = tid & 7;
    const int c = tid >> 3;
    float p = 0.f;
#pragma unroll
    for (int q = 0; q < 8; ++q) p = fmaf(hv[c * 8 + q], Wfc[(size_t)n * FEAT + c * 8 + q], p);
    ps[tid] = p;
    __syncthreads();
    if (tid < 8) {
        float s = bfc[tid];
        for (int q = 0; q < 32; ++q) s += ps[tid + 8 * q];
        out[(size_t)b * NCLS + tid] = s;
    }
}

// ---------------------------------------------------------------------------
extern "C" void kernel_launch(void* const* d_in, const int* in_sizes, int n_in,
                              void* d_out, int out_size, void* d_ws, size_t ws_size,
                              hipStream_t stream) {
    const int* x      = (const int*)d_in[0];
    const float* emb  = (const float*)d_in[1];
    const float* A    = (const float*)d_in[2];
    const float* Wh   = (const float*)d_in[3];
    const float* Wc   = (const float*)d_in[4];
    const float* tb   = (const float*)d_in[5];
    const float* Wfc  = (const float*)d_in[6];
    const float* bfc  = (const float*)d_in[7];
    float* out = (float*)d_out;

    // workspace layout (16B-aligned)
    unsigned short* ex16  = (unsigned short*)d_ws;            // B*S*E + 2*E pad
    unsigned short* Whk16 = ex16 + (size_t)B * S * E + 2 * E; // FEAT*3*E
    float* scores = (float*)(Whk16 + (size_t)FEAT * 3 * E);   // B*S*ATT
    float* attn   = scores + (size_t)B * S * ATT;             // B*S*ATT
    float* Cpart  = attn + (size_t)B * S * ATT;               // B*FEAT*8
    float* hc     = Cpart + (size_t)B * FEAT * 8;             // B*FEAT

    k_prep<<<FEAT, 256, 0, stream>>>(Wh, Whk16, ex16);
    k_embed<<<B * S, 64, 0, stream>>>(x, emb, A, ex16, scores, attn);
    k_conv<<<dim3(B, 2, 4), 256, 0, stream>>>(Whk16, ex16, Cpart);
    k_chc<<<dim3(FEAT, B), 64, 0, stream>>>(scores, attn, Wc, Cpart, tb, hc);
    k_out<<<B, 256, 0, stream>>>(hc, Wfc, bfc, out);
}